// Round 5
// baseline (174.721 us; speedup 1.0000x reference)
//
#include <hip/hip_runtime.h>

#define NPARC 289
#define NOUT  578
#define DIMK  512
#define CTILES 40          // pad 578 -> 640 output cols (zeros)
#define BATCH 32768

typedef __bf16 bf16x8 __attribute__((ext_vector_type(8)));
typedef float floatx4 __attribute__((ext_vector_type(4)));

__device__ __forceinline__ unsigned short f2bf(float f) {
    unsigned u = __float_as_uint(f);
    u = (u + 0x7fffu + ((u >> 16) & 1u)) >> 16;
    return (unsigned short)u;
}

// Wp layout: [ct][ks][lane][8] bf16 — MFMA fragment order (identical for A/B
// operands of mfma_f32_16x16x32_bf16): m/n = ct*16 + (lane&15),
// k = ks*32 + (lane>>4)*8 + j.  Cols >= 578 zero-filled.
// One wave per column: lane reads 8 consecutive floats (coalesced 2 KB/col).
__global__ void prep_w(const float* __restrict__ W, unsigned short* __restrict__ Wp) {
    int wid = threadIdx.x >> 6;
    int lane = threadIdx.x & 63;
    int col = blockIdx.x * 4 + wid;          // [0, 640)
    int k = lane * 8;
    unsigned short v[8];
    if (col < NOUT) {
        const float* src = W + (size_t)col * DIMK + k;
        #pragma unroll
        for (int j = 0; j < 8; ++j) v[j] = f2bf(src[j]);
    } else {
        #pragma unroll
        for (int j = 0; j < 8; ++j) v[j] = 0;
    }
    int ct = col >> 4;
    int ks = k >> 5;
    int ln = (((k >> 3) & 3) << 4) + (col & 15);
    uint4 o;
    o.x = (unsigned)v[0] | ((unsigned)v[1] << 16);
    o.y = (unsigned)v[2] | ((unsigned)v[3] << 16);
    o.z = (unsigned)v[4] | ((unsigned)v[5] << 16);
    o.w = (unsigned)v[6] | ((unsigned)v[7] << 16);
    *(uint4*)(Wp + (size_t)((ct * 16 + ks) * 64 + ln) * 8) = o;
}

// Fused GEMM + |S|^2/(4*sum p^2) epilogue.
// A = W fragments (M = weight cols), B = input tile from LDS (N = samples).
// C/D: row (quad*4+reg) = weight col, col (lane&15) = sample.
// Round 5: __sincosf -> __sinf/__cosf. The pointer out-params of __sincosf
// forced a scratch stack slot per call (45.7 MB/dispatch of private-memory
// writes = 160 calls/thread x ~9 B). Value-returning intrinsics lower to
// pure v_sin_f32/v_cos_f32 — no scratch.
__global__ __launch_bounds__(256, 2) void fused_kernel(
    const float* __restrict__ inputs, const float* __restrict__ targets,
    const float* __restrict__ bias, const unsigned short* __restrict__ Wp,
    float* __restrict__ out)
{
    __shared__ __align__(16) unsigned short Alds[64 * 64 * 8];   // 64 KiB
    const int tid = threadIdx.x;
    const int base = blockIdx.x * 64;

    // ---- stage inputs: fp32 -> bf16 into LDS in fragment order ----
    const float4* inp4 = (const float4*)(inputs + (size_t)base * DIMK);
    #pragma unroll
    for (int i = 0; i < 32; ++i) {
        int f = i * 256 + tid;            // [0, 8192) float4s = 64 rows * 128
        int s = f >> 7;                   // local sample
        int k = (f & 127) * 4;            // k % 4 == 0
        float4 v = inp4[f];
        int t = ((s >> 4) << 4) + (k >> 5);
        int ln = ((((k >> 3) & 3) << 4) + (s & 15)) ^ (t & 7);
        int off = (t * 64 + ln) * 8 + (k & 7);
        uint2 w;
        w.x = (unsigned)f2bf(v.x) | ((unsigned)f2bf(v.y) << 16);
        w.y = (unsigned)f2bf(v.z) | ((unsigned)f2bf(v.w) << 16);
        *(uint2*)&Alds[off] = w;
    }
    __syncthreads();

    const int wid  = tid >> 6;
    const int lane = tid & 63;
    const int quad = lane >> 4;
    const int lcol = lane & 15;

    // this lane's sample per sample-tile: base + st*16 + lcol
    float xs[4], ys[4];
    #pragma unroll
    for (int st = 0; st < 4; ++st) {
        float2 t2 = *(const float2*)(targets + 2 * (base + st * 16 + lcol));
        xs[st] = t2.x;
        ys[st] = t2.y;
    }

    float pd[4] = {0.f,0.f,0.f,0.f};   // sum p^2        (per sample-tile)
    float pr[4] = {0.f,0.f,0.f,0.f};   // Re S
    float pim[4] = {0.f,0.f,0.f,0.f};  // Im S

    const bf16x8* Wf = (const bf16x8*)Wp;

    #pragma unroll 1
    for (int pp = 0; pp < 5; ++pp) {           // 2 weight-col tiles per pass
        const int wct0 = wid * 10 + pp * 2;
        floatx4 acc[2][4];
        #pragma unroll
        for (int w2 = 0; w2 < 2; ++w2)
            #pragma unroll
            for (int st = 0; st < 4; ++st) acc[w2][st] = (floatx4){0.f,0.f,0.f,0.f};

        #pragma unroll
        for (int ks = 0; ks < 16; ++ks) {
            bf16x8 aw[2], bs[4];
            #pragma unroll
            for (int w2 = 0; w2 < 2; ++w2)
                aw[w2] = Wf[(size_t)(((wct0 + w2) * 16 + ks) * 64 + lane)];
            #pragma unroll
            for (int st = 0; st < 4; ++st) {
                int t = st * 16 + ks;
                bs[st] = *(const bf16x8*)&Alds[(t * 64 + (lane ^ (t & 7))) * 8];
            }
            #pragma unroll
            for (int w2 = 0; w2 < 2; ++w2)
                #pragma unroll
                for (int st = 0; st < 4; ++st)
                    acc[w2][st] = __builtin_amdgcn_mfma_f32_16x16x32_bf16(
                        aw[w2], bs[st], acc[w2][st], 0, 0, 0);
        }

        // epilogue: fold these 2 weight-col tiles into per-sample partials
        #pragma unroll
        for (int w2 = 0; w2 < 2; ++w2)
            #pragma unroll
            for (int reg = 0; reg < 4; ++reg) {
                int colw = (wct0 + w2) * 16 + quad * 4 + reg;
                if (colw < NOUT) {
                    bool im = (colw >= NPARC);
                    int idx = im ? colw - NPARC : colw;
                    int r = idx / 17;
                    int c = idx - r * 17;
                    float cf = (float)c, rf = (float)r;
                    float bb = bias[colw];
                    #pragma unroll
                    for (int st = 0; st < 4; ++st) {
                        float val = acc[w2][st][reg] + bb;
                        float phi = 3.14159265358979323846f * fmaf(cf, xs[st], rf * ys[st]);
                        float sn = __sinf(phi);
                        float cs = __cosf(phi);
                        float a1 = im ? -sn : cs;
                        float a2 = im ?  cs : sn;
                        pd[st]  = fmaf(val, val, pd[st]);
                        pr[st]  = fmaf(val, a1, pr[st]);
                        pim[st] = fmaf(val, a2, pim[st]);
                    }
                }
            }
    }

    // reduce across the 4 quads (weight-col rows) — butterfly on lane bits 4,5
    #pragma unroll
    for (int d = 16; d < 64; d <<= 1)
        #pragma unroll
        for (int st = 0; st < 4; ++st) {
            pd[st]  += __shfl_xor(pd[st], d, 64);
            pr[st]  += __shfl_xor(pr[st], d, 64);
            pim[st] += __shfl_xor(pim[st], d, 64);
        }

    __syncthreads();                       // all waves done reading Alds
    float* R = (float*)Alds;               // [wave][64 samples][3]
    if (lane < 16) {
        #pragma unroll
        for (int st = 0; st < 4; ++st) {
            int sl = st * 16 + lane;
            R[(wid * 64 + sl) * 3 + 0] = pd[st];
            R[(wid * 64 + sl) * 3 + 1] = pr[st];
            R[(wid * 64 + sl) * 3 + 2] = pim[st];
        }
    }
    __syncthreads();

    if (tid < 64) {
        float sd = 0.f, sr = 0.f, si = 0.f;
        #pragma unroll
        for (int w = 0; w < 4; ++w) {
            sd += R[(w * 64 + tid) * 3 + 0];
            sr += R[(w * 64 + tid) * 3 + 1];
            si += R[(w * 64 + tid) * 3 + 2];
        }
        out[base + tid] = (sr * sr + si * si) / (4.0f * sd);
    }
}

extern "C" void kernel_launch(void* const* d_in, const int* in_sizes, int n_in,
                              void* d_out, int out_size, void* d_ws, size_t ws_size,
                              hipStream_t stream) {
    const float* inputs  = (const float*)d_in[0];
    const float* targets = (const float*)d_in[1];
    const float* W       = (const float*)d_in[2];
    const float* bias    = (const float*)d_in[3];
    unsigned short* Wp   = (unsigned short*)d_ws;   // 640 KiB of ws

    prep_w<<<CTILES * 16 / 4, 256, 0, stream>>>(W, Wp);
    fused_kernel<<<BATCH / 64, 256, 0, stream>>>(inputs, targets, bias, Wp, (float*)d_out);
}

// Round 6
// 122.475 us; speedup vs baseline: 1.4266x; 1.4266x over previous
//
#include <hip/hip_runtime.h>

#define NPARC 289
#define NOUT  578
#define DIMK  512
#define CTILES 40          // pad 578 -> 640 output cols (zeros)
#define BATCH 32768

typedef __bf16 bf16x8 __attribute__((ext_vector_type(8)));
typedef float floatx4 __attribute__((ext_vector_type(4)));

__device__ __forceinline__ unsigned short f2bf(float f) {
    unsigned u = __float_as_uint(f);
    u = (u + 0x7fffu + ((u >> 16) & 1u)) >> 16;
    return (unsigned short)u;
}

// Wp layout: [ct][ks][lane][8] bf16 — MFMA fragment order (identical for A/B
// operands of mfma_f32_16x16x32_bf16): m/n = ct*16 + (lane&15),
// k = ks*32 + (lane>>4)*8 + j.  Cols >= 578 zero-filled.
__global__ void prep_w(const float* __restrict__ W, unsigned short* __restrict__ Wp) {
    int wid = threadIdx.x >> 6;
    int lane = threadIdx.x & 63;
    int col = blockIdx.x * 4 + wid;          // [0, 640)
    int k = lane * 8;
    unsigned short v[8];
    if (col < NOUT) {
        const float* src = W + (size_t)col * DIMK + k;
        #pragma unroll
        for (int j = 0; j < 8; ++j) v[j] = f2bf(src[j]);
    } else {
        #pragma unroll
        for (int j = 0; j < 8; ++j) v[j] = 0;
    }
    int ct = col >> 4;
    int ks = k >> 5;
    int ln = (((k >> 3) & 3) << 4) + (col & 15);
    uint4 o;
    o.x = (unsigned)v[0] | ((unsigned)v[1] << 16);
    o.y = (unsigned)v[2] | ((unsigned)v[3] << 16);
    o.z = (unsigned)v[4] | ((unsigned)v[5] << 16);
    o.w = (unsigned)v[6] | ((unsigned)v[7] << 16);
    *(uint4*)(Wp + (size_t)((ct * 16 + ks) * 64 + ln) * 8) = o;
}

// Fused GEMM + |S|^2/(4*sum p^2) epilogue.
// A = W fragments (M = weight cols), B = input tile from LDS (N = samples).
// C/D: row (quad*4+reg) = weight col, col (lane&15) = sample.
// ROUND 6: ks loop unroll bounded to 4. Full unroll (16 iters x 6 loads x
// 8 regs) let the scheduler keep ~100 load-result VGPRs in flight ->
// transient pressure > the 128-reg cap -> per-iteration scratch spill
// (45.7 MB/dispatch HBM writes in R4/R5, 119 MB in R2/R3). unroll 4 bounds
// the in-flight window to ~48 regs; 8 waves/CU TLP covers the rest.
__global__ __launch_bounds__(256, 2) void fused_kernel(
    const float* __restrict__ inputs, const float* __restrict__ targets,
    const float* __restrict__ bias, const unsigned short* __restrict__ Wp,
    float* __restrict__ out)
{
    __shared__ __align__(16) unsigned short Alds[64 * 64 * 8];   // 64 KiB
    const int tid = threadIdx.x;
    const int base = blockIdx.x * 64;

    // ---- stage inputs: fp32 -> bf16 into LDS in fragment order ----
    const float4* inp4 = (const float4*)(inputs + (size_t)base * DIMK);
    #pragma unroll
    for (int i = 0; i < 32; ++i) {
        int f = i * 256 + tid;            // [0, 8192) float4s = 64 rows * 128
        int s = f >> 7;                   // local sample
        int k = (f & 127) * 4;            // k % 4 == 0
        float4 v = inp4[f];
        int t = ((s >> 4) << 4) + (k >> 5);
        int ln = ((((k >> 3) & 3) << 4) + (s & 15)) ^ (t & 7);
        int off = (t * 64 + ln) * 8 + (k & 7);
        uint2 w;
        w.x = (unsigned)f2bf(v.x) | ((unsigned)f2bf(v.y) << 16);
        w.y = (unsigned)f2bf(v.z) | ((unsigned)f2bf(v.w) << 16);
        *(uint2*)&Alds[off] = w;
    }
    __syncthreads();

    const int wid  = tid >> 6;
    const int lane = tid & 63;
    const int quad = lane >> 4;
    const int lcol = lane & 15;

    // this lane's sample per sample-tile: base + st*16 + lcol
    float xs[4], ys[4];
    #pragma unroll
    for (int st = 0; st < 4; ++st) {
        float2 t2 = *(const float2*)(targets + 2 * (base + st * 16 + lcol));
        xs[st] = t2.x;
        ys[st] = t2.y;
    }

    float pd[4] = {0.f,0.f,0.f,0.f};   // sum p^2        (per sample-tile)
    float pr[4] = {0.f,0.f,0.f,0.f};   // Re S
    float pim[4] = {0.f,0.f,0.f,0.f};  // Im S

    const bf16x8* Wf = (const bf16x8*)Wp;

    #pragma unroll 1
    for (int pp = 0; pp < 5; ++pp) {           // 2 weight-col tiles per pass
        const int wct0 = wid * 10 + pp * 2;
        floatx4 acc[2][4];
        #pragma unroll
        for (int w2 = 0; w2 < 2; ++w2)
            #pragma unroll
            for (int st = 0; st < 4; ++st) acc[w2][st] = (floatx4){0.f,0.f,0.f,0.f};

        const bf16x8* awp = Wf + ((size_t)(wct0 * 16) * 64 + lane);

        #pragma unroll 4
        for (int ks = 0; ks < 16; ++ks) {
            bf16x8 aw[2], bs[4];
            #pragma unroll
            for (int w2 = 0; w2 < 2; ++w2)
                aw[w2] = awp[(size_t)(w2 * 16 + ks) * 64];
            #pragma unroll
            for (int st = 0; st < 4; ++st) {
                int t = st * 16 + ks;
                bs[st] = *(const bf16x8*)&Alds[(t * 64 + (lane ^ (t & 7))) * 8];
            }
            #pragma unroll
            for (int w2 = 0; w2 < 2; ++w2)
                #pragma unroll
                for (int st = 0; st < 4; ++st)
                    acc[w2][st] = __builtin_amdgcn_mfma_f32_16x16x32_bf16(
                        aw[w2], bs[st], acc[w2][st], 0, 0, 0);
        }

        // epilogue: fold these 2 weight-col tiles into per-sample partials
        #pragma unroll
        for (int w2 = 0; w2 < 2; ++w2)
            #pragma unroll
            for (int reg = 0; reg < 4; ++reg) {
                int colw = (wct0 + w2) * 16 + quad * 4 + reg;
                if (colw < NOUT) {
                    bool im = (colw >= NPARC);
                    int idx = im ? colw - NPARC : colw;
                    int r = idx / 17;
                    int c = idx - r * 17;
                    float cf = (float)c, rf = (float)r;
                    float bb = bias[colw];
                    #pragma unroll
                    for (int st = 0; st < 4; ++st) {
                        float val = acc[w2][st][reg] + bb;
                        float phi = 3.14159265358979323846f * fmaf(cf, xs[st], rf * ys[st]);
                        float sn = __sinf(phi);
                        float cs = __cosf(phi);
                        float a1 = im ? -sn : cs;
                        float a2 = im ?  cs : sn;
                        pd[st]  = fmaf(val, val, pd[st]);
                        pr[st]  = fmaf(val, a1, pr[st]);
                        pim[st] = fmaf(val, a2, pim[st]);
                    }
                }
            }
    }

    // reduce across the 4 quads (weight-col rows) — butterfly on lane bits 4,5
    #pragma unroll
    for (int d = 16; d < 64; d <<= 1)
        #pragma unroll
        for (int st = 0; st < 4; ++st) {
            pd[st]  += __shfl_xor(pd[st], d, 64);
            pr[st]  += __shfl_xor(pr[st], d, 64);
            pim[st] += __shfl_xor(pim[st], d, 64);
        }

    __syncthreads();                       // all waves done reading Alds
    float* R = (float*)Alds;               // [wave][64 samples][3]
    if (lane < 16) {
        #pragma unroll
        for (int st = 0; st < 4; ++st) {
            int sl = st * 16 + lane;
            R[(wid * 64 + sl) * 3 + 0] = pd[st];
            R[(wid * 64 + sl) * 3 + 1] = pr[st];
            R[(wid * 64 + sl) * 3 + 2] = pim[st];
        }
    }
    __syncthreads();

    if (tid < 64) {
        float sd = 0.f, sr = 0.f, si = 0.f;
        #pragma unroll
        for (int w = 0; w < 4; ++w) {
            sd += R[(w * 64 + tid) * 3 + 0];
            sr += R[(w * 64 + tid) * 3 + 1];
            si += R[(w * 64 + tid) * 3 + 2];
        }
        out[base + tid] = (sr * sr + si * si) / (4.0f * sd);
    }
}

extern "C" void kernel_launch(void* const* d_in, const int* in_sizes, int n_in,
                              void* d_out, int out_size, void* d_ws, size_t ws_size,
                              hipStream_t stream) {
    const float* inputs  = (const float*)d_in[0];
    const float* targets = (const float*)d_in[1];
    const float* W       = (const float*)d_in[2];
    const float* bias    = (const float*)d_in[3];
    unsigned short* Wp   = (unsigned short*)d_ws;   // 640 KiB of ws

    prep_w<<<CTILES * 16 / 4, 256, 0, stream>>>(W, Wp);
    fused_kernel<<<BATCH / 64, 256, 0, stream>>>(inputs, targets, bias, Wp, (float*)d_out);
}